// Round 10
// baseline (283.304 us; speedup 1.0000x reference)
//
#include <hip/hip_runtime.h>
#include <cstddef>

#define T_STEPS 256
#define OBS     32
#define ACTD    8
#define NB      16      // sequences per block (full N-dim of transposed MFMA)
#define HPAD    72      // h row stride in f16 (144 B)
#define NSEQ    4096

typedef _Float16 f16x8 __attribute__((ext_vector_type(8)));
typedef _Float16 f16x2 __attribute__((ext_vector_type(2)));
typedef float    f32x4 __attribute__((ext_vector_type(4)));

union F8 { f16x8 v; _Float16 e[8]; f16x2 h2[4]; };

#define LOG2E 1.44269504088896f

__device__ __forceinline__ float fsig(float x) {
    return __builtin_amdgcn_rcpf(1.0f + __builtin_amdgcn_exp2f(x * -LOG2E));
}
__device__ __forceinline__ float ftanh(float x) {
    return 2.0f * __builtin_amdgcn_rcpf(1.0f + __builtin_amdgcn_exp2f(x * (-2.0f * LOG2E))) - 1.0f;
}
__device__ __forceinline__ f16x2 pkrtz(float a, float b) {
    return __builtin_bit_cast(f16x2, __builtin_amdgcn_cvt_pkrtz(a, b));
}

__global__ __launch_bounds__(256)
void lstm_fused(const float* __restrict__ obss, const float* __restrict__ actions,
                const float* __restrict__ W, const float* __restrict__ b,
                const float* __restrict__ Wdec, const float* __restrict__ bdec_p,
                float* __restrict__ out)
{
    // Transposed GEMM: D[gate-col][seq] = W^T (A, static regs) x [h|x]^T (B).
    // h LDS: row = seq, col = phi(unit); phi(u)=(u&3)+4*((u>>4)&1)+8*((u>>2)&3)+32*(u>>5)
    __shared__ __align__(16) _Float16 Ahi[2][NB * HPAD];
    __shared__ __align__(16) _Float16 Alo[2][NB * HPAD];
    __shared__ float partb[2][16][20];    // [buf][seq][16 partials]

    const int tid  = threadIdx.x;
    const int w    = tid >> 6;            // wave 0..3
    const int lane = tid & 63;
    const int g    = lane >> 4;           // k-group / D-row-group
    const int m    = lane & 15;           // seq (B col / D col); A row = gate-col 64e+16w+m
    const int n0   = blockIdx.x * NB;
    const int u0   = 16 * w + 4 * g;      // first of 4 units this lane updates
    const int sigb = 32 * (w >> 1) + 8 * g + 4 * (w & 1);  // = phi(u0)

    // ---- one-time: W^T fragments as A operands (plain f16; h hi/lo is B-side) ----
    f16x8 Ahh[4][2], Axo[4], AxA[4];
    {
        const float* Wc = W + 16 * w + m;     // tile e -> gate-col 64e + 16w + m
#pragma unroll
        for (int e = 0; e < 4; e++) {
#pragma unroll
            for (int c = 0; c < 2; c++) {
                F8 hi;
#pragma unroll
                for (int i = 0; i < 8; i++) {
                    int k = 32 * c + 16 * (i >> 2) + 4 * g + (i & 3);  // h-k 0..63
                    hi.e[i] = (_Float16)Wc[(40 + k) * 256 + 64 * e];
                }
                Ahh[e][c] = hi.v;
            }
            F8 xo, xA;
#pragma unroll
            for (int i = 0; i < 8; i++) {
                int d = 16 * (i >> 2) + 4 * g + (i & 3);               // 0..31
                xo.e[i] = (_Float16)Wc[d * 256 + 64 * e];
                xA.e[i] = (d < ACTD) ? (_Float16)Wc[(OBS + d) * 256 + 64 * e]
                                     : (_Float16)0.0f;                 // act, zero-padded K32
            }
            Axo[e] = xo.v;
            AxA[e] = xA.v;
        }
    }
    // per-lane vector biases / decode weights for units u0..u0+3
    f32x4 bIv = *(const f32x4*)&b[u0];
    f32x4 bJv = *(const f32x4*)&b[64 + u0];
    f32x4 bFv = *(const f32x4*)&b[128 + u0];
    bFv[0] += 1.0f; bFv[1] += 1.0f; bFv[2] += 1.0f; bFv[3] += 1.0f;
    f32x4 bOv = *(const f32x4*)&b[192 + u0];
    f32x4 wdv = *(const f32x4*)&Wdec[u0];
    const float bd = bdec_p[0];

    for (int i = tid; i < 2 * NB * HPAD; i += 256) {
        (&Ahi[0][0])[i] = (_Float16)0.0f;
        (&Alo[0][0])[i] = (_Float16)0.0f;
    }
    __syncthreads();

    // per-lane x prefetch: seq m, dim-slice by g; running pointers
    const float* pO = obss    + ((size_t)(n0 + m) * T_STEPS) * OBS  + 4 * g;
    const float* pA = actions + ((size_t)(n0 + m) * T_STEPS) * ACTD + 4 * g;
    f32x4 xo0 = {0,0,0,0}, xo1 = {0,0,0,0}, xa = {0,0,0,0};
    auto loadx = [&]() {
        xo0 = *(const f32x4*)pO;
        xo1 = *(const f32x4*)(pO + 16);
        pO += OBS;
        if (g < 2) { xa = *(const f32x4*)pA; pA += ACTD; }
    };
    loadx();
    f32x4 cr = {0.f, 0.f, 0.f, 0.f};      // c state: units u0..u0+3 of seq m
    float* pOut = out + n0 + tid;         // running output pointer (tid<16 lanes)

#pragma unroll 2
    for (int t = 0; t < T_STEPS; ++t) {
        const int cb  = t & 1;
        const int nb2 = cb ^ 1;
        // LDS-only barrier: x prefetch (vmcnt) may span it
        asm volatile("s_waitcnt lgkmcnt(0)\n\ts_barrier" ::: "memory");

        // B h-fragments: seq row m, phi-contiguous b128 slices (cols 0..63)
        const _Float16* bh = &Ahi[cb][m * HPAD];
        const _Float16* bl = &Alo[cb][m * HPAD];
        f16x8 bh0 = *(const f16x8*)(bh + 8 * g);          // k 0..31
        f16x8 bh1 = *(const f16x8*)(bh + 32 + 8 * g);     // k 32..63
        f16x8 bl0 = *(const f16x8*)(bl + 8 * g);
        f16x8 bl1 = *(const f16x8*)(bl + 32 + 8 * g);

        if (t > 0 && tid < 16) {
            float o = bd;
#pragma unroll
            for (int k2 = 0; k2 < 16; k2++) o += partb[nb2][tid][k2];
            *pOut = o;
            pOut += NSEQ;
        }

        // B x-fragments from prefetched regs (packed cvt; act zero-padded to K32)
        F8 uo;
        uo.h2[0] = pkrtz(xo0[0], xo0[1]);
        uo.h2[1] = pkrtz(xo0[2], xo0[3]);
        uo.h2[2] = pkrtz(xo1[0], xo1[1]);
        uo.h2[3] = pkrtz(xo1[2], xo1[3]);
        F8 uA;
        uA.h2[0] = pkrtz(xa[0], xa[1]);
        uA.h2[1] = pkrtz(xa[2], xa[3]);
        uA.h2[2] = pkrtz(0.0f, 0.0f);
        uA.h2[3] = pkrtz(0.0f, 0.0f);
        f16x8 bxo = uo.v;
        f16x8 bxA = uA.v;
        if (t + 1 < T_STEPS) loadx();

        // 4 independent tiles (gate e), single 6-deep K32 chain each
        f32x4 acc[4];
        __builtin_amdgcn_s_setprio(1);
#pragma unroll
        for (int e = 0; e < 4; e++) {
            f32x4 a = {0.f, 0.f, 0.f, 0.f};
            a = __builtin_amdgcn_mfma_f32_16x16x32_f16(Axo[e], bxo, a, 0, 0, 0);
            a = __builtin_amdgcn_mfma_f32_16x16x32_f16(AxA[e], bxA, a, 0, 0, 0);
            a = __builtin_amdgcn_mfma_f32_16x16x32_f16(Ahh[e][0], bh0, a, 0, 0, 0);
            a = __builtin_amdgcn_mfma_f32_16x16x32_f16(Ahh[e][1], bh1, a, 0, 0, 0);
            a = __builtin_amdgcn_mfma_f32_16x16x32_f16(Ahh[e][0], bl0, a, 0, 0, 0);
            a = __builtin_amdgcn_mfma_f32_16x16x32_f16(Ahh[e][1], bl1, a, 0, 0, 0);
            acc[e] = a;
        }
        __builtin_amdgcn_s_setprio(0);

        // cell update: 4 units (u0+r) of seq m; scalar h/lo writes (R3-proven pattern)
        float p = 0.0f;
#pragma unroll
        for (int r = 0; r < 4; r++) {
            float gi = acc[0][r] + bIv[r];
            float gj = acc[1][r] + bJv[r];
            float gf = acc[2][r] + bFv[r];
            float go = acc[3][r] + bOv[r];
            float c  = cr[r] * fsig(gf) + fsig(gi) * ftanh(gj);
            cr[r] = c;
            float h = ftanh(c) * fsig(go);
            _Float16 hv = (_Float16)h;
            Ahi[nb2][m * HPAD + sigb + r] = hv;
            Alo[nb2][m * HPAD + sigb + r] = (_Float16)(h - (float)hv);
            p = fmaf(h, wdv[r], p);
        }
        partb[cb][m][4 * w + g] = p;
    }

    __syncthreads();
    if (tid < 16) {
        float o = bd;
#pragma unroll
        for (int k2 = 0; k2 < 16; k2++) o += partb[1][tid][k2];
        *pOut = o;
    }
}

extern "C" void kernel_launch(void* const* d_in, const int* in_sizes, int n_in,
                              void* d_out, int out_size, void* d_ws, size_t ws_size,
                              hipStream_t stream) {
    (void)in_sizes; (void)n_in; (void)d_ws; (void)ws_size; (void)out_size;
    const float* obss    = (const float*)d_in[0];
    const float* actions = (const float*)d_in[1];
    const float* W       = (const float*)d_in[2];
    const float* b       = (const float*)d_in[3];
    const float* Wdec    = (const float*)d_in[4];
    const float* bdec    = (const float*)d_in[5];
    float* out = (float*)d_out;
    lstm_fused<<<dim3(NSEQ / NB), dim3(256), 0, stream>>>(obss, actions, W, b, Wdec, bdec, out);
}